// Round 5
// baseline (1591.274 us; speedup 1.0000x reference)
//
#include <hip/hip_runtime.h>
#include <hip/hip_bf16.h>

// ---------------------------------------------------------------------------
// HybridCnnLnn R20: fill the CU — 2 blocks/CU, 1 batch per block.
// Ledger: R19 1122us, VALUBusy 83%, VGPR 52 (compiler streams tables from L2
// regardless; "tables in regs" never materialized). Issue model fit: trans
// (exp2/rcp) ~16 cyc/wave64 => ~80% of VALU issue is transcendental; issue
// floor ~900us. Remaining lever = the 17% idle (1 block/CU, 4 waves/SIMD,
// barrier/butterfly tails exposed). R20: grid 512, ONE batch per 1024-thr
// block -> 2 independent blocks/CU (2048 thr/CU, 8 waves/SIMD): one block's
// barrier tails hide under the other's issue. Also: feats fully staged to
// LDS up front (35KB, kills in-loop prefetch), single-batch butterfly = 6
// shfl/unfold. Per-eval ops + accumulation order unchanged -> absmax 0.0.
// amdgpu_waves_per_eu(8) caps VGPR at 64 (R19 used 52 for a heavier loop).
// Tripwires: Occupancy ~46 => 2nd block didn't fit; MB WRITE_SIZE => spill.
// ---------------------------------------------------------------------------

#define L2E 1.4426950408889634f

// ---------------- prep: fold params, transpose to [n][j*8+h] ---------------
__global__ __launch_bounds__(256)
void prep_kernel(const float* __restrict__ smu, const float* __restrict__ ssig,
                 const float* __restrict__ sW,  const float* __restrict__ serev,
                 const float* __restrict__ mu,  const float* __restrict__ sig,
                 const float* __restrict__ W,   const float* __restrict__ erev,
                 const float* __restrict__ in_w, const float* __restrict__ in_b,
                 float2* __restrict__ R12T, float* __restrict__ VTT,
                 float2* __restrict__ S2T, float* __restrict__ SWT) {
  int idx = blockIdx.x * 256 + threadIdx.x;      // idx = i*128 + j
  int i = idx >> 7, j = idx & 127;
  int h = i >> 4, n = i & 15;
  int dst = n * 1024 + j * 8 + h;                // lane-major for lnn mapping
  float r1 = sig[idx] * L2E;
  R12T[dst] = make_float2(r1, mu[idx] * r1);     // arg = r2 - r1*v
  VTT[dst]  = W[idx] * erev[idx];                // |erev|=1 -> |VT| = W
  float ss = ssig[idx] * L2E;
  S2T[dst] = make_float2(ss * in_w[i], (smu[idx] - in_b[i]) * ss);
  SWT[dst] = sW[idx] * serev[idx];
}

// ----------------------------- conv1 (k=5, tiled) --------------------------
// x [512,256,24] -> P1 [512,64,128] ([b][co][t']), relu+maxpool2 fused
__launch_bounds__(512)
__global__ void conv1_kernel(const float* __restrict__ x, const float* __restrict__ w1,
                             const float* __restrict__ b1, float* __restrict__ P1) {
  __shared__ float xs[6240];                     // rows t in [-2,258), 24 ch
  int tid = threadIdx.x, b = blockIdx.x;
  const float* xb = x + (size_t)b * 6144;
  for (int idx = tid; idx < 6144; idx += 512) xs[idx + 48] = xb[idx];
  if (tid < 48) { xs[tid] = 0.f; xs[6192 + tid] = 0.f; }
  __syncthreads();
  int tp = tid & 127, cq = tid >> 7;             // 128 pooled t x 4 co-quarters
  float acc0[16], acc1[16];
#pragma unroll
  for (int n = 0; n < 16; n++) { float bb = b1[cq * 16 + n]; acc0[n] = bb; acc1[n] = bb; }
  for (int cic = 0; cic < 3; cic++) {            // ci chunks of 8
    float p[6][8];
#pragma unroll
    for (int r = 0; r < 6; r++) {
      const float* row = &xs[(2 * tp + r) * 24 + cic * 8];
      float4 a = *(const float4*)row;
      float4 c = *(const float4*)(row + 4);
      p[r][0] = a.x; p[r][1] = a.y; p[r][2] = a.z; p[r][3] = a.w;
      p[r][4] = c.x; p[r][5] = c.y; p[r][6] = c.z; p[r][7] = c.w;
    }
#pragma unroll
    for (int n = 0; n < 16; n++) {
      const float* wr = w1 + (cq * 16 + n) * 120 + cic * 40;  // uniform -> s_load
#pragma unroll
      for (int c = 0; c < 8; c++) {
#pragma unroll
        for (int kk = 0; kk < 5; kk++) {
          float w = wr[c * 5 + kk];
          acc0[n] = fmaf(p[kk][c],     w, acc0[n]);
          acc1[n] = fmaf(p[kk + 1][c], w, acc1[n]);
        }
      }
    }
  }
  float* pb = P1 + (size_t)b * 8192;
#pragma unroll
  for (int n = 0; n < 16; n++)
    pb[(cq * 16 + n) * 128 + tp] = fmaxf(fmaxf(acc0[n], acc1[n]), 0.f);
}

// ----------------------------- conv2 (k=3, tiled) --------------------------
// P1 [512,64,128] -> feats [512,64,128] laid out [b][t'][co]
__launch_bounds__(512)
__global__ void conv2_kernel(const float* __restrict__ P1, const float* __restrict__ w2,
                             const float* __restrict__ b2, float* __restrict__ feats) {
  __shared__ float xs[8450];                     // [t+1][ci], stride 65
  int tid = threadIdx.x, b = blockIdx.x;
  const float* pb = P1 + (size_t)b * 8192;
  for (int idx = tid; idx < 8192; idx += 512) {
    int ci = idx >> 7, t = idx & 127;
    xs[(t + 1) * 65 + ci] = pb[idx];
  }
  if (tid < 65) { xs[tid] = 0.f; xs[129 * 65 + tid] = 0.f; }
  __syncthreads();
  int tp = tid & 63, cq = tid >> 6;              // 64 pooled t x 8 co-octants
  float acc0[16], acc1[16];
#pragma unroll
  for (int n = 0; n < 16; n++) { float bb = b2[cq * 16 + n]; acc0[n] = bb; acc1[n] = bb; }
  for (int cic = 0; cic < 8; cic++) {            // ci chunks of 8
    float p[4][8];
#pragma unroll
    for (int r = 0; r < 4; r++)
#pragma unroll
      for (int c = 0; c < 8; c++)
        p[r][c] = xs[(2 * tp + r) * 65 + cic * 8 + c];
#pragma unroll
    for (int n = 0; n < 16; n++) {
      const float* wr = w2 + (cq * 16 + n) * 192 + cic * 24;  // native [co][ci][kk]
#pragma unroll
      for (int c = 0; c < 8; c++) {
#pragma unroll
        for (int kk = 0; kk < 3; kk++) {
          float w = wr[c * 3 + kk];
          acc0[n] = fmaf(p[kk][c],     w, acc0[n]);
          acc1[n] = fmaf(p[kk + 1][c], w, acc1[n]);
        }
      }
    }
  }
  __syncthreads();                               // reuse xs as [tp][co]
#pragma unroll
  for (int n = 0; n < 16; n += 4) {
    float4 v;
    v.x = fmaxf(fmaxf(acc0[n],     acc1[n]),     0.f);
    v.y = fmaxf(fmaxf(acc0[n + 1], acc1[n + 1]), 0.f);
    v.z = fmaxf(fmaxf(acc0[n + 2], acc1[n + 2]), 0.f);
    v.w = fmaxf(fmaxf(acc0[n + 3], acc1[n + 3]), 0.f);
    *(float4*)&xs[tp * 128 + cq * 16 + n] = v;
  }
  __syncthreads();
  float* fb = feats + (size_t)b * 8192;
  for (int idx = tid; idx < 8192; idx += 512) fb[idx] = xs[idx];
}

// --------------------------- LTC recurrence + head -------------------------
// block = 1024 = 128 j x 8 h, ONE batch per block, grid 512 -> 2 blocks/CU
// (8 waves/SIMD). All 64 t of feats staged to LDS once. Tables streamed from
// L2 (compiler-preferred, R19-proven 52 VGPR). Per-unfold: 16 eval iters ->
// 3-stage shfl_xor butterfly (2 vars) -> h==0 leader update -> ONE barrier.
__global__ void __launch_bounds__(1024) __attribute__((amdgpu_waves_per_eu(8)))
lnn_kernel(const float2* __restrict__ R12T, const float* __restrict__ VTT,
           const float2* __restrict__ S2T, const float* __restrict__ SWT,
           const float* __restrict__ feats,
           const float* __restrict__ cm_t, const float* __restrict__ gleak,
           const float* __restrict__ vleak,
           const float* __restrict__ fc1_w, const float* __restrict__ fc1_b,
           const float* __restrict__ fc2_w, const float* __restrict__ fc2_b,
           float* __restrict__ out) {
  __shared__ float xt_all[64][136];              // all t, padded slots: 34.8KB
  __shared__ float vbuf[2][136];                 // ping-pong v, padded slots
  __shared__ float red[64];
  int tid = threadIdx.x;
  int h = tid & 7, j = tid >> 3;
  int b = blockIdx.x;

  // stage the whole batch's feats (coalesced reads, slotted writes)
  {
    const float* fb = feats + (size_t)b * 8192;
    for (int idx = tid; idx < 8192; idx += 1024) {
      int t = idx >> 7, u = idx & 127;
      xt_all[t][u + (u >> 4)] = fb[idx];
    }
  }

  float cmj = cm_t[j], glk = gleak[j];
  float gvl = glk * vleak[j], cgl = cmj + glk;
  float vj = 0.f;
  if (tid < 136) vbuf[0][tid] = 0.f;
  __syncthreads();

  const int hb = 17 * h;                         // slot base: 16h + n + h
  const float2* s2p = S2T + tid;
  const float*  swp = SWT + tid;
  const float2* rp  = R12T + tid;
  const float*  vwp = VTT + tid;

  for (int t = 0; t < 64; t++) {
    // ---- sensory partials (tables streamed from L2; xt broadcast) ----
    float sn = 0.f, sd = 0.f;
    {
      const float* xb = xt_all[t];
#pragma unroll 8
      for (int n = 0; n < 16; n++) {
        float2 s = s2p[n * 1024];
        float w = swp[n * 1024];
        float xv = xb[hb + n];
        float q = __builtin_amdgcn_rcpf(1.f + __builtin_amdgcn_exp2f(fmaf(-s.x, xv, s.y)));
        sn = fmaf(w, q, sn); sd = fmaf(fabsf(w), q, sd);
      }
    }

    // ---- 6 semi-implicit ODE unfolds ----
    for (int u = 0; u < 6; u++) {
      float n0 = sn, d0 = sd;
      const float* vb = vbuf[u & 1] + hb;
#pragma unroll
      for (int n = 0; n < 16; n++) {
        float2 rr = rp[n * 1024];                // L2 stream (t-invariant, hot)
        float vw = vwp[n * 1024];
        float v2 = vb[n];                        // 8-addr broadcast, conflict-free
        float q = __builtin_amdgcn_rcpf(1.f + __builtin_amdgcn_exp2f(fmaf(-rr.x, v2, rr.y)));
        n0 = fmaf(vw, q, n0); d0 = fmaf(fabsf(vw), q, d0);
      }
      // butterfly allreduce over the 8 octant lanes
#pragma unroll
      for (int m = 1; m < 8; m <<= 1) {
        n0 += __shfl_xor(n0, m, 64);
        d0 += __shfl_xor(d0, m, 64);
      }
      if (h == 0) {                              // leader lane per unit
        float den = cgl + d0;
        float ii = __builtin_amdgcn_rcpf(den); ii = ii * fmaf(-den, ii, 2.f);
        vj = (fmaf(cmj, vj, gvl) + n0) * ii;
        vbuf[(u + 1) & 1][j + (j >> 4)] = vj;
      }
      __syncthreads();                           // the ONLY barrier per unfold
    }
  }

  // ---- MLP head (final v sits in vbuf[0] after 6 flips) ----
  if (tid < 64) {
    float acc = fc1_b[tid];
    for (int u = 0; u < 128; u++)
      acc = fmaf(vbuf[0][u + (u >> 4)], fc1_w[tid * 128 + u], acc);
    red[tid] = fmaxf(acc, 0.f) * fc2_w[tid];
  }
  __syncthreads();
  if (tid == 0) {
    float s = fc2_b[0];
    for (int d = 0; d < 64; d++) s += red[d];
    out[b] = s;
  }
}

// ------------------------------- launcher ----------------------------------
extern "C" void kernel_launch(void* const* d_in, const int* in_sizes, int n_in,
                              void* d_out, int out_size, void* d_ws, size_t ws_size,
                              hipStream_t stream) {
  (void)in_sizes; (void)n_in; (void)out_size; (void)ws_size;
  char* ws = (char*)d_ws;
  // 32MB envelope, time-multiplexed:
  //   P1 [0,16M) live conv1->conv2; tables [0,384K) after conv2 (prep);
  //   feats [16M,32M) live conv2->lnn.
  float*  P1   = (float*)(ws);
  float*  feats= (float*)(ws + (16 << 20));
  float2* R12T = (float2*)(ws + 0);             // 128KB
  float*  VTT  = (float*)(ws + (128 << 10));    // 64KB
  float2* S2T  = (float2*)(ws + (192 << 10));   // 128KB
  float*  SWT  = (float*)(ws + (320 << 10));    // 64KB -> ends 384KB

  conv1_kernel<<<512, 512, 0, stream>>>((const float*)d_in[0],
      (const float*)d_in[1], (const float*)d_in[2], P1);
  conv2_kernel<<<512, 512, 0, stream>>>(P1,
      (const float*)d_in[3], (const float*)d_in[4], feats);
  prep_kernel<<<64, 256, 0, stream>>>(
      (const float*)d_in[7], (const float*)d_in[8],
      (const float*)d_in[9], (const float*)d_in[10],
      (const float*)d_in[11], (const float*)d_in[12],
      (const float*)d_in[13], (const float*)d_in[14],
      (const float*)d_in[5], (const float*)d_in[6],
      R12T, VTT, S2T, SWT);
  lnn_kernel<<<512, 1024, 0, stream>>>(R12T, VTT, S2T, SWT, feats,
      (const float*)d_in[17], (const float*)d_in[16], (const float*)d_in[15],
      (const float*)d_in[18], (const float*)d_in[19],
      (const float*)d_in[20], (const float*)d_in[21],
      (float*)d_out);
}

// Round 6
// 1254.894 us; speedup vs baseline: 1.2681x; 1.2681x over previous
//
#include <hip/hip_runtime.h>
#include <hip/hip_bf16.h>

// ---------------------------------------------------------------------------
// HybridCnnLnn R21: R19 + asm-pinned unfold tables (the no-reload structure).
// Ledger: R15 1085 (lnn), R18 1179 (r12 LDS), R19 1122 (all streamed, 83%
// busy), R20 1470 (1 batch/block: spill + 2x table L2 traffic; occupancy
// path closed — 8 waves/SIMD needs ~40TB/s L2 > 34.5 ceiling).
// R19's 17% idle = per-unfold cold-start: compiler drains vmcnt(0) before
// every s_barrier, so table loads re-issue and stall every one of 384
// rounds, all 16 waves together. Fix: r12+vw pinned in 48 VGPRs via
// asm volatile("" : "+v"(x)) — opaque to rematerialization, CANNOT be sunk
// back into the loop (R19's failure mode). Unfold inner loop: zero VMEM.
// Sensory stream back to R15's packed float4 (16 VMEM/phase, -1 addr
// stream). Est. live set 85-95 regs under the waves_per_eu(4,4) 128 budget.
// This round is also the decisive budget experiment:
//   VGPR ~85-100 + KB-scale WRITE => budget 128, pin worked.
//   VGPR 64 + MB-scale WRITE      => budget hard-capped, revert pin.
// Arithmetic op-for-op identical to R19 -> absmax 0.0 expected.
// ---------------------------------------------------------------------------

#define L2E 1.4426950408889634f

// ---------------- prep: fold params, transpose to [n][j*8+h] ---------------
__global__ __launch_bounds__(256)
void prep_kernel(const float* __restrict__ smu, const float* __restrict__ ssig,
                 const float* __restrict__ sW,  const float* __restrict__ serev,
                 const float* __restrict__ mu,  const float* __restrict__ sig,
                 const float* __restrict__ W,   const float* __restrict__ erev,
                 const float* __restrict__ in_w, const float* __restrict__ in_b,
                 float2* __restrict__ R12T, float* __restrict__ VTT,
                 float4* __restrict__ S4T) {
  int idx = blockIdx.x * 256 + threadIdx.x;      // idx = i*128 + j
  int i = idx >> 7, j = idx & 127;
  int h = i >> 4, n = i & 15;
  int dst = n * 1024 + j * 8 + h;                // lane-major for lnn mapping
  float r1 = sig[idx] * L2E;
  R12T[dst] = make_float2(r1, mu[idx] * r1);     // arg = r2 - r1*v
  VTT[dst]  = W[idx] * erev[idx];                // |erev|=1 -> |VT| = W
  float ss = ssig[idx] * L2E;
  S4T[dst] = make_float4(ss * in_w[i], (smu[idx] - in_b[i]) * ss,
                         sW[idx] * serev[idx], 0.f);
}

// ----------------------------- conv1 (k=5, tiled) --------------------------
// x [512,256,24] -> P1 [512,64,128] ([b][co][t']), relu+maxpool2 fused
__launch_bounds__(512)
__global__ void conv1_kernel(const float* __restrict__ x, const float* __restrict__ w1,
                             const float* __restrict__ b1, float* __restrict__ P1) {
  __shared__ float xs[6240];                     // rows t in [-2,258), 24 ch
  int tid = threadIdx.x, b = blockIdx.x;
  const float* xb = x + (size_t)b * 6144;
  for (int idx = tid; idx < 6144; idx += 512) xs[idx + 48] = xb[idx];
  if (tid < 48) { xs[tid] = 0.f; xs[6192 + tid] = 0.f; }
  __syncthreads();
  int tp = tid & 127, cq = tid >> 7;             // 128 pooled t x 4 co-quarters
  float acc0[16], acc1[16];
#pragma unroll
  for (int n = 0; n < 16; n++) { float bb = b1[cq * 16 + n]; acc0[n] = bb; acc1[n] = bb; }
  for (int cic = 0; cic < 3; cic++) {            // ci chunks of 8
    float p[6][8];
#pragma unroll
    for (int r = 0; r < 6; r++) {
      const float* row = &xs[(2 * tp + r) * 24 + cic * 8];
      float4 a = *(const float4*)row;
      float4 c = *(const float4*)(row + 4);
      p[r][0] = a.x; p[r][1] = a.y; p[r][2] = a.z; p[r][3] = a.w;
      p[r][4] = c.x; p[r][5] = c.y; p[r][6] = c.z; p[r][7] = c.w;
    }
#pragma unroll
    for (int n = 0; n < 16; n++) {
      const float* wr = w1 + (cq * 16 + n) * 120 + cic * 40;  // uniform -> s_load
#pragma unroll
      for (int c = 0; c < 8; c++) {
#pragma unroll
        for (int kk = 0; kk < 5; kk++) {
          float w = wr[c * 5 + kk];
          acc0[n] = fmaf(p[kk][c],     w, acc0[n]);
          acc1[n] = fmaf(p[kk + 1][c], w, acc1[n]);
        }
      }
    }
  }
  float* pb = P1 + (size_t)b * 8192;
#pragma unroll
  for (int n = 0; n < 16; n++)
    pb[(cq * 16 + n) * 128 + tp] = fmaxf(fmaxf(acc0[n], acc1[n]), 0.f);
}

// ----------------------------- conv2 (k=3, tiled) --------------------------
// P1 [512,64,128] -> feats [512,64,128] laid out [b][t'][co]
__launch_bounds__(512)
__global__ void conv2_kernel(const float* __restrict__ P1, const float* __restrict__ w2,
                             const float* __restrict__ b2, float* __restrict__ feats) {
  __shared__ float xs[8450];                     // [t+1][ci], stride 65
  int tid = threadIdx.x, b = blockIdx.x;
  const float* pb = P1 + (size_t)b * 8192;
  for (int idx = tid; idx < 8192; idx += 512) {
    int ci = idx >> 7, t = idx & 127;
    xs[(t + 1) * 65 + ci] = pb[idx];
  }
  if (tid < 65) { xs[tid] = 0.f; xs[129 * 65 + tid] = 0.f; }
  __syncthreads();
  int tp = tid & 63, cq = tid >> 6;              // 64 pooled t x 8 co-octants
  float acc0[16], acc1[16];
#pragma unroll
  for (int n = 0; n < 16; n++) { float bb = b2[cq * 16 + n]; acc0[n] = bb; acc1[n] = bb; }
  for (int cic = 0; cic < 8; cic++) {            // ci chunks of 8
    float p[4][8];
#pragma unroll
    for (int r = 0; r < 4; r++)
#pragma unroll
      for (int c = 0; c < 8; c++)
        p[r][c] = xs[(2 * tp + r) * 65 + cic * 8 + c];
#pragma unroll
    for (int n = 0; n < 16; n++) {
      const float* wr = w2 + (cq * 16 + n) * 192 + cic * 24;  // native [co][ci][kk]
#pragma unroll
      for (int c = 0; c < 8; c++) {
#pragma unroll
        for (int kk = 0; kk < 3; kk++) {
          float w = wr[c * 3 + kk];
          acc0[n] = fmaf(p[kk][c],     w, acc0[n]);
          acc1[n] = fmaf(p[kk + 1][c], w, acc1[n]);
        }
      }
    }
  }
  __syncthreads();                               // reuse xs as [tp][co]
#pragma unroll
  for (int n = 0; n < 16; n += 4) {
    float4 v;
    v.x = fmaxf(fmaxf(acc0[n],     acc1[n]),     0.f);
    v.y = fmaxf(fmaxf(acc0[n + 1], acc1[n + 1]), 0.f);
    v.z = fmaxf(fmaxf(acc0[n + 2], acc1[n + 2]), 0.f);
    v.w = fmaxf(fmaxf(acc0[n + 3], acc1[n + 3]), 0.f);
    *(float4*)&xs[tp * 128 + cq * 16 + n] = v;
  }
  __syncthreads();
  float* fb = feats + (size_t)b * 8192;
  for (int idx = tid; idx < 8192; idx += 512) fb[idx] = xs[idx];
}

// --------------------------- LTC recurrence + head -------------------------
// block = 1024: h = tid&7 (i-octant), j = tid>>3 (unit). 2 batches/block,
// grid 256 = 1 block/CU, waves_per_eu(4,4) -> 128-VGPR budget. r12+vw
// asm-PINNED in 48 VGPRs (no reload, no per-unfold VMEM bubble). Sensory S4
// streamed packed-float4 from L2. Per-unfold: 16 pure-reg iters + broadcast
// vbuf read -> 3x shfl_xor butterfly -> h<2 dual-lane leader -> ONE barrier.
__global__ void __launch_bounds__(1024) __attribute__((amdgpu_waves_per_eu(4, 4)))
lnn_kernel(const float2* __restrict__ R12T, const float* __restrict__ VTT,
           const float4* __restrict__ S4T,
           const float* __restrict__ feats,
           const float* __restrict__ cm_t, const float* __restrict__ gleak,
           const float* __restrict__ vleak,
           const float* __restrict__ fc1_w, const float* __restrict__ fc1_b,
           const float* __restrict__ fc2_w, const float* __restrict__ fc2_b,
           float* __restrict__ out) {
  __shared__ float2 xt2[2][136];                 // feats double-buffer, padded
  __shared__ float2 vbuf[2][136];                // ping-pong v, padded slots
  __shared__ float red[2][64];
  int tid = threadIdx.x;
  int h = tid & 7, j = tid >> 3;
  int b0 = blockIdx.x * 2;

  // unfold tables -> 48 VGPRs, then PIN (opaque to remat/sinking)
  float2 r12[16]; float vw[16];
#pragma unroll
  for (int n = 0; n < 16; n++) {
    r12[n] = R12T[n * 1024 + tid];
    vw[n]  = VTT[n * 1024 + tid];
  }
#pragma unroll
  for (int n = 0; n < 16; n++)
    asm volatile("" : "+v"(r12[n].x), "+v"(r12[n].y), "+v"(vw[n]));

  float cmj = cm_t[j], glk = gleak[j];
  float gvl = glk * vleak[j], cgl = cmj + glk;
  float vj0 = 0.f, vj1 = 0.f;
  if (tid < 136) vbuf[0][tid] = make_float2(0.f, 0.f);
  const float* f0 = feats + (size_t)b0 * 8192;
  const float* f1 = f0 + 8192;
  if (tid < 128) xt2[0][tid + (tid >> 4)] = make_float2(f0[tid], f1[tid]);
  __syncthreads();

  const int hb = 17 * h;                         // slot base: 16h + n + h
  const float4* sp = S4T + tid;

  for (int t = 0; t < 64; t++) {
    // prefetch feats for t+1; LDS-write parked at unfold u=4
    float pf0 = 0.f, pf1 = 0.f;
    if (tid < 128 && t < 63) {
      pf0 = f0[(t + 1) * 128 + tid];
      pf1 = f1[(t + 1) * 128 + tid];
    }

    // ---- sensory partials (packed S4 streamed from L2; R15 shape) ----
    float sn0 = 0.f, sd0 = 0.f, sn1 = 0.f, sd1 = 0.f;
    {
      const float2* xb = xt2[t & 1];
#pragma unroll 8
      for (int n = 0; n < 16; n++) {
        float4 s = sp[n * 1024];
        float2 xv = xb[hb + n];
        float q0 = __builtin_amdgcn_rcpf(1.f + __builtin_amdgcn_exp2f(fmaf(-s.x, xv.x, s.y)));
        sn0 = fmaf(s.z, q0, sn0); sd0 = fmaf(fabsf(s.z), q0, sd0);
        float q1 = __builtin_amdgcn_rcpf(1.f + __builtin_amdgcn_exp2f(fmaf(-s.x, xv.y, s.y)));
        sn1 = fmaf(s.z, q1, sn1); sd1 = fmaf(fabsf(s.z), q1, sd1);
      }
    }

    // ---- 6 semi-implicit ODE unfolds (zero-VMEM inner loop) ----
    for (int u = 0; u < 6; u++) {
      float n0 = sn0, d0 = sd0, n1 = sn1, d1 = sd1;
      const float2* vb = vbuf[u & 1] + hb;
#pragma unroll
      for (int n = 0; n < 16; n++) {
        float2 rr = r12[n];                      // pinned registers
        float2 v2 = vb[n];                       // 8-addr broadcast, conflict-free
        float q0 = __builtin_amdgcn_rcpf(1.f + __builtin_amdgcn_exp2f(fmaf(-rr.x, v2.x, rr.y)));
        n0 = fmaf(vw[n], q0, n0); d0 = fmaf(fabsf(vw[n]), q0, d0);
        float q1 = __builtin_amdgcn_rcpf(1.f + __builtin_amdgcn_exp2f(fmaf(-rr.x, v2.y, rr.y)));
        n1 = fmaf(vw[n], q1, n1); d1 = fmaf(fabsf(vw[n]), q1, d1);
      }
      // butterfly allreduce over the 8 octant lanes (bit-identical per lane)
#pragma unroll
      for (int m = 1; m < 8; m <<= 1) {
        n0 += __shfl_xor(n0, m, 64);
        d0 += __shfl_xor(d0, m, 64);
        n1 += __shfl_xor(n1, m, 64);
        d1 += __shfl_xor(d1, m, 64);
      }
      if (u == 4 && tid < 128 && t < 63)         // park prefetched feats
        xt2[(t + 1) & 1][tid + (tid >> 4)] = make_float2(pf0, pf1);
      if (h < 2) {                               // dual-lane leader: batch = h
        float nn = h ? n1 : n0, dd = h ? d1 : d0;
        float vj = h ? vj1 : vj0;
        float den = cgl + dd;
        float ii = __builtin_amdgcn_rcpf(den); ii = ii * fmaf(-den, ii, 2.f);
        vj = (fmaf(cmj, vj, gvl) + nn) * ii;
        if (h) vj1 = vj; else vj0 = vj;
        ((float*)vbuf[(u + 1) & 1])[(j + (j >> 4)) * 2 + h] = vj;
      }
      __syncthreads();                           // the ONLY barrier per unfold
    }
  }

  // ---- MLP head (final v sits in vbuf[0] after 6 flips) ----
  if (tid < 128) {
    int g = tid >> 6, d = tid & 63;
    float acc = fc1_b[d];
    for (int u = 0; u < 128; u++) {
      float2 v2 = vbuf[0][u + (u >> 4)];
      acc = fmaf(g ? v2.y : v2.x, fc1_w[d * 128 + u], acc);
    }
    red[g][d] = fmaxf(acc, 0.f) * fc2_w[d];
  }
  __syncthreads();
  if (tid < 2) {
    float s = fc2_b[0];
    for (int d = 0; d < 64; d++) s += red[tid][d];
    out[b0 + tid] = s;
  }
}

// ------------------------------- launcher ----------------------------------
extern "C" void kernel_launch(void* const* d_in, const int* in_sizes, int n_in,
                              void* d_out, int out_size, void* d_ws, size_t ws_size,
                              hipStream_t stream) {
  (void)in_sizes; (void)n_in; (void)out_size; (void)ws_size;
  char* ws = (char*)d_ws;
  // 32MB envelope, time-multiplexed:
  //   P1 [0,16M) live conv1->conv2; tables [0,448K) after conv2 (prep);
  //   feats [16M,32M) live conv2->lnn.
  float*  P1   = (float*)(ws);
  float*  feats= (float*)(ws + (16 << 20));
  float2* R12T = (float2*)(ws + 0);             // 128KB
  float*  VTT  = (float*)(ws + (128 << 10));    // 64KB
  float4* S4T  = (float4*)(ws + (192 << 10));   // 256KB -> ends 448KB

  conv1_kernel<<<512, 512, 0, stream>>>((const float*)d_in[0],
      (const float*)d_in[1], (const float*)d_in[2], P1);
  conv2_kernel<<<512, 512, 0, stream>>>(P1,
      (const float*)d_in[3], (const float*)d_in[4], feats);
  prep_kernel<<<64, 256, 0, stream>>>(
      (const float*)d_in[7], (const float*)d_in[8],
      (const float*)d_in[9], (const float*)d_in[10],
      (const float*)d_in[11], (const float*)d_in[12],
      (const float*)d_in[13], (const float*)d_in[14],
      (const float*)d_in[5], (const float*)d_in[6],
      R12T, VTT, S4T);
  lnn_kernel<<<256, 1024, 0, stream>>>(R12T, VTT, S4T, feats,
      (const float*)d_in[17], (const float*)d_in[16], (const float*)d_in[15],
      (const float*)d_in[18], (const float*)d_in[19],
      (const float*)d_in[20], (const float*)d_in[21],
      (float*)d_out);
}

// Round 8
// 1253.147 us; speedup vs baseline: 1.2698x; 1.0014x over previous
//
#include <hip/hip_runtime.h>
#include <hip/hip_bf16.h>

// ---------------------------------------------------------------------------
// HybridCnnLnn R23 (= R22 with DPP ctrl as template arg; compile fix only).
// Ledger: R21 1101us lnn, VGPR 64, zero spill, busy 918us (83%). Model:
// 37.5 cyc/eval, 32 of which = exp2+rcp at ~16 issue-cyc each => trans-bound.
// R23a: 4-way rcp batching — one rcp(E0*E1*E2*E3) + NR + 11 muls replaces
//   4 rcps for the (n,n+1)x(b0,b1) group: 160->134 cyc per 4 evals (-16%).
//   Numerics: shared rcp NR-refined; ~2-3ulp per sigmoid vs hw rcp ->
//   absmax ~1e-5 expected (no longer 0.0).
// R23b: DPP butterfly — v_add+quad_perm(0xB1,0x4E)+row_half_mirror(0x141)
//   replaces 24 serial ds_swizzle/round (bit-exact: stage-3 addend is the
//   quad total on every source lane). Cuts ~90cyc DS chain x384 rounds.
// Keep: asm-pinned r12/vw (48 VGPR), dual-lane leader, 1 barrier/unfold,
// S4 float4 L2 stream, feats double-buffer. waves_per_eu(4,4), 128 budget.
// ---------------------------------------------------------------------------

#define L2E 1.4426950408889634f

template <int CTRL>
__device__ __forceinline__ float dpp_add(float x) {
  int y = __builtin_amdgcn_update_dpp(0, __float_as_int(x), CTRL, 0xF, 0xF, false);
  return x + __int_as_float(y);
}
#define DPP_SWAP1  0xB1   // quad_perm [1,0,3,2]
#define DPP_SWAP2  0x4E   // quad_perm [2,3,0,1]
#define DPP_HALFM  0x141  // row_half_mirror (cross-quad within 8 lanes)

// ---------------- prep: fold params, transpose to [n][j*8+h] ---------------
__global__ __launch_bounds__(256)
void prep_kernel(const float* __restrict__ smu, const float* __restrict__ ssig,
                 const float* __restrict__ sW,  const float* __restrict__ serev,
                 const float* __restrict__ mu,  const float* __restrict__ sig,
                 const float* __restrict__ W,   const float* __restrict__ erev,
                 const float* __restrict__ in_w, const float* __restrict__ in_b,
                 float2* __restrict__ R12T, float* __restrict__ VTT,
                 float4* __restrict__ S4T) {
  int idx = blockIdx.x * 256 + threadIdx.x;      // idx = i*128 + j
  int i = idx >> 7, j = idx & 127;
  int h = i >> 4, n = i & 15;
  int dst = n * 1024 + j * 8 + h;                // lane-major for lnn mapping
  float r1 = sig[idx] * L2E;
  R12T[dst] = make_float2(r1, mu[idx] * r1);     // arg = r2 - r1*v
  VTT[dst]  = W[idx] * erev[idx];                // |erev|=1 -> |VT| = W
  float ss = ssig[idx] * L2E;
  S4T[dst] = make_float4(ss * in_w[i], (smu[idx] - in_b[i]) * ss,
                         sW[idx] * serev[idx], 0.f);
}

// ----------------------------- conv1 (k=5, tiled) --------------------------
// x [512,256,24] -> P1 [512,64,128] ([b][co][t']), relu+maxpool2 fused
__launch_bounds__(512)
__global__ void conv1_kernel(const float* __restrict__ x, const float* __restrict__ w1,
                             const float* __restrict__ b1, float* __restrict__ P1) {
  __shared__ float xs[6240];                     // rows t in [-2,258), 24 ch
  int tid = threadIdx.x, b = blockIdx.x;
  const float* xb = x + (size_t)b * 6144;
  for (int idx = tid; idx < 6144; idx += 512) xs[idx + 48] = xb[idx];
  if (tid < 48) { xs[tid] = 0.f; xs[6192 + tid] = 0.f; }
  __syncthreads();
  int tp = tid & 127, cq = tid >> 7;             // 128 pooled t x 4 co-quarters
  float acc0[16], acc1[16];
#pragma unroll
  for (int n = 0; n < 16; n++) { float bb = b1[cq * 16 + n]; acc0[n] = bb; acc1[n] = bb; }
  for (int cic = 0; cic < 3; cic++) {            // ci chunks of 8
    float p[6][8];
#pragma unroll
    for (int r = 0; r < 6; r++) {
      const float* row = &xs[(2 * tp + r) * 24 + cic * 8];
      float4 a = *(const float4*)row;
      float4 c = *(const float4*)(row + 4);
      p[r][0] = a.x; p[r][1] = a.y; p[r][2] = a.z; p[r][3] = a.w;
      p[r][4] = c.x; p[r][5] = c.y; p[r][6] = c.z; p[r][7] = c.w;
    }
#pragma unroll
    for (int n = 0; n < 16; n++) {
      const float* wr = w1 + (cq * 16 + n) * 120 + cic * 40;  // uniform -> s_load
#pragma unroll
      for (int c = 0; c < 8; c++) {
#pragma unroll
        for (int kk = 0; kk < 5; kk++) {
          float w = wr[c * 5 + kk];
          acc0[n] = fmaf(p[kk][c],     w, acc0[n]);
          acc1[n] = fmaf(p[kk + 1][c], w, acc1[n]);
        }
      }
    }
  }
  float* pb = P1 + (size_t)b * 8192;
#pragma unroll
  for (int n = 0; n < 16; n++)
    pb[(cq * 16 + n) * 128 + tp] = fmaxf(fmaxf(acc0[n], acc1[n]), 0.f);
}

// ----------------------------- conv2 (k=3, tiled) --------------------------
// P1 [512,64,128] -> feats [512,64,128] laid out [b][t'][co]
__launch_bounds__(512)
__global__ void conv2_kernel(const float* __restrict__ P1, const float* __restrict__ w2,
                             const float* __restrict__ b2, float* __restrict__ feats) {
  __shared__ float xs[8450];                     // [t+1][ci], stride 65
  int tid = threadIdx.x, b = blockIdx.x;
  const float* pb = P1 + (size_t)b * 8192;
  for (int idx = tid; idx < 8192; idx += 512) {
    int ci = idx >> 7, t = idx & 127;
    xs[(t + 1) * 65 + ci] = pb[idx];
  }
  if (tid < 65) { xs[tid] = 0.f; xs[129 * 65 + tid] = 0.f; }
  __syncthreads();
  int tp = tid & 63, cq = tid >> 6;              // 64 pooled t x 8 co-octants
  float acc0[16], acc1[16];
#pragma unroll
  for (int n = 0; n < 16; n++) { float bb = b2[cq * 16 + n]; acc0[n] = bb; acc1[n] = bb; }
  for (int cic = 0; cic < 8; cic++) {            // ci chunks of 8
    float p[4][8];
#pragma unroll
    for (int r = 0; r < 4; r++)
#pragma unroll
      for (int c = 0; c < 8; c++)
        p[r][c] = xs[(2 * tp + r) * 65 + cic * 8 + c];
#pragma unroll
    for (int n = 0; n < 16; n++) {
      const float* wr = w2 + (cq * 16 + n) * 192 + cic * 24;  // native [co][ci][kk]
#pragma unroll
      for (int c = 0; c < 8; c++) {
#pragma unroll
        for (int kk = 0; kk < 3; kk++) {
          float w = wr[c * 3 + kk];
          acc0[n] = fmaf(p[kk][c],     w, acc0[n]);
          acc1[n] = fmaf(p[kk + 1][c], w, acc1[n]);
        }
      }
    }
  }
  __syncthreads();                               // reuse xs as [tp][co]
#pragma unroll
  for (int n = 0; n < 16; n += 4) {
    float4 v;
    v.x = fmaxf(fmaxf(acc0[n],     acc1[n]),     0.f);
    v.y = fmaxf(fmaxf(acc0[n + 1], acc1[n + 1]), 0.f);
    v.z = fmaxf(fmaxf(acc0[n + 2], acc1[n + 2]), 0.f);
    v.w = fmaxf(fmaxf(acc0[n + 3], acc1[n + 3]), 0.f);
    *(float4*)&xs[tp * 128 + cq * 16 + n] = v;
  }
  __syncthreads();
  float* fb = feats + (size_t)b * 8192;
  for (int idx = tid; idx < 8192; idx += 512) fb[idx] = xs[idx];
}

// --------------------------- LTC recurrence + head -------------------------
// block = 1024: h = tid&7 (i-octant), j = tid>>3 (unit). 2 batches/block,
// grid 256 = 1 block/CU, waves_per_eu(4,4) -> 128-VGPR budget. r12+vw
// asm-pinned (48 VGPR). 4-way-rcp eval groups; DPP butterfly allreduce;
// dual-lane leader; ONE barrier per unfold.
__global__ void __launch_bounds__(1024) __attribute__((amdgpu_waves_per_eu(4, 4)))
lnn_kernel(const float2* __restrict__ R12T, const float* __restrict__ VTT,
           const float4* __restrict__ S4T,
           const float* __restrict__ feats,
           const float* __restrict__ cm_t, const float* __restrict__ gleak,
           const float* __restrict__ vleak,
           const float* __restrict__ fc1_w, const float* __restrict__ fc1_b,
           const float* __restrict__ fc2_w, const float* __restrict__ fc2_b,
           float* __restrict__ out) {
  __shared__ float2 xt2[2][136];                 // feats double-buffer, padded
  __shared__ float2 vbuf[2][136];                // ping-pong v, padded slots
  __shared__ float red[2][64];
  int tid = threadIdx.x;
  int h = tid & 7, j = tid >> 3;
  int b0 = blockIdx.x * 2;

  // unfold tables -> 48 VGPRs, then PIN (opaque to remat/sinking)
  float2 r12[16]; float vw[16];
#pragma unroll
  for (int n = 0; n < 16; n++) {
    r12[n] = R12T[n * 1024 + tid];
    vw[n]  = VTT[n * 1024 + tid];
  }
#pragma unroll
  for (int n = 0; n < 16; n++)
    asm volatile("" : "+v"(r12[n].x), "+v"(r12[n].y), "+v"(vw[n]));

  float cmj = cm_t[j], glk = gleak[j];
  float gvl = glk * vleak[j], cgl = cmj + glk;
  float vj0 = 0.f, vj1 = 0.f;
  if (tid < 136) vbuf[0][tid] = make_float2(0.f, 0.f);
  const float* f0 = feats + (size_t)b0 * 8192;
  const float* f1 = f0 + 8192;
  if (tid < 128) xt2[0][tid + (tid >> 4)] = make_float2(f0[tid], f1[tid]);
  __syncthreads();

  const int hb = 17 * h;                         // slot base: 16h + n + h
  const float4* sp = S4T + tid;

  for (int t = 0; t < 64; t++) {
    // prefetch feats for t+1; LDS-write parked at unfold u=4
    float pf0 = 0.f, pf1 = 0.f;
    if (tid < 128 && t < 63) {
      pf0 = f0[(t + 1) * 128 + tid];
      pf1 = f1[(t + 1) * 128 + tid];
    }

    // ---- sensory partials (S4 stream; 4-way rcp batching) ----
    float sn0 = 0.f, sd0 = 0.f, sn1 = 0.f, sd1 = 0.f;
    {
      const float2* xb = xt2[t & 1];
#pragma unroll
      for (int n = 0; n < 16; n += 2) {
        float4 sA = sp[n * 1024];
        float4 sB = sp[(n + 1) * 1024];
        float2 xA = xb[hb + n];
        float2 xB = xb[hb + n + 1];
        float EA0 = 1.f + __builtin_amdgcn_exp2f(fmaf(-sA.x, xA.x, sA.y));
        float EA1 = 1.f + __builtin_amdgcn_exp2f(fmaf(-sA.x, xA.y, sA.y));
        float EB0 = 1.f + __builtin_amdgcn_exp2f(fmaf(-sB.x, xB.x, sB.y));
        float EB1 = 1.f + __builtin_amdgcn_exp2f(fmaf(-sB.x, xB.y, sB.y));
        float DA = EA0 * EA1, DB = EB0 * EB1, D = DA * DB;
        float r = __builtin_amdgcn_rcpf(D);
        r = r * fmaf(-D, r, 2.f);                // NR: ~1ulp of 1/D
        float tA = DB * r, tB = DA * r;
        float qA0 = EA1 * tA, qA1 = EA0 * tA;
        float qB0 = EB1 * tB, qB1 = EB0 * tB;
        sn0 = fmaf(sA.z, qA0, sn0); sd0 = fmaf(fabsf(sA.z), qA0, sd0);
        sn1 = fmaf(sA.z, qA1, sn1); sd1 = fmaf(fabsf(sA.z), qA1, sd1);
        sn0 = fmaf(sB.z, qB0, sn0); sd0 = fmaf(fabsf(sB.z), qB0, sd0);
        sn1 = fmaf(sB.z, qB1, sn1); sd1 = fmaf(fabsf(sB.z), qB1, sd1);
      }
    }

    // ---- 6 semi-implicit ODE unfolds (zero-VMEM, 4-way rcp groups) ----
    for (int u = 0; u < 6; u++) {
      float n0 = sn0, d0 = sd0, n1 = sn1, d1 = sd1;
      const float2* vb = vbuf[u & 1] + hb;
#pragma unroll
      for (int n = 0; n < 16; n += 2) {
        float2 rrA = r12[n], rrB = r12[n + 1];
        float2 vA = vb[n], vB = vb[n + 1];
        float EA0 = 1.f + __builtin_amdgcn_exp2f(fmaf(-rrA.x, vA.x, rrA.y));
        float EA1 = 1.f + __builtin_amdgcn_exp2f(fmaf(-rrA.x, vA.y, rrA.y));
        float EB0 = 1.f + __builtin_amdgcn_exp2f(fmaf(-rrB.x, vB.x, rrB.y));
        float EB1 = 1.f + __builtin_amdgcn_exp2f(fmaf(-rrB.x, vB.y, rrB.y));
        float DA = EA0 * EA1, DB = EB0 * EB1, D = DA * DB;
        float r = __builtin_amdgcn_rcpf(D);
        r = r * fmaf(-D, r, 2.f);
        float tA = DB * r, tB = DA * r;
        float qA0 = EA1 * tA, qA1 = EA0 * tA;
        float qB0 = EB1 * tB, qB1 = EB0 * tB;
        n0 = fmaf(vw[n], qA0, n0); d0 = fmaf(fabsf(vw[n]), qA0, d0);
        n1 = fmaf(vw[n], qA1, n1); d1 = fmaf(fabsf(vw[n]), qA1, d1);
        n0 = fmaf(vw[n + 1], qB0, n0); d0 = fmaf(fabsf(vw[n + 1]), qB0, d0);
        n1 = fmaf(vw[n + 1], qB1, n1); d1 = fmaf(fabsf(vw[n + 1]), qB1, d1);
      }
      // DPP butterfly allreduce over the 8 octant lanes (bit-exact vs shfl)
      n0 = dpp_add<DPP_SWAP1>(n0); d0 = dpp_add<DPP_SWAP1>(d0);
      n1 = dpp_add<DPP_SWAP1>(n1); d1 = dpp_add<DPP_SWAP1>(d1);
      n0 = dpp_add<DPP_SWAP2>(n0); d0 = dpp_add<DPP_SWAP2>(d0);
      n1 = dpp_add<DPP_SWAP2>(n1); d1 = dpp_add<DPP_SWAP2>(d1);
      n0 = dpp_add<DPP_HALFM>(n0); d0 = dpp_add<DPP_HALFM>(d0);
      n1 = dpp_add<DPP_HALFM>(n1); d1 = dpp_add<DPP_HALFM>(d1);
      if (u == 4 && tid < 128 && t < 63)         // park prefetched feats
        xt2[(t + 1) & 1][tid + (tid >> 4)] = make_float2(pf0, pf1);
      if (h < 2) {                               // dual-lane leader: batch = h
        float nn = h ? n1 : n0, dd = h ? d1 : d0;
        float vj = h ? vj1 : vj0;
        float den = cgl + dd;
        float ii = __builtin_amdgcn_rcpf(den); ii = ii * fmaf(-den, ii, 2.f);
        vj = (fmaf(cmj, vj, gvl) + nn) * ii;
        if (h) vj1 = vj; else vj0 = vj;
        ((float*)vbuf[(u + 1) & 1])[(j + (j >> 4)) * 2 + h] = vj;
      }
      __syncthreads();                           // the ONLY barrier per unfold
    }
  }

  // ---- MLP head (final v sits in vbuf[0] after 6 flips) ----
  if (tid < 128) {
    int g = tid >> 6, d = tid & 63;
    float acc = fc1_b[d];
    for (int u = 0; u < 128; u++) {
      float2 v2 = vbuf[0][u + (u >> 4)];
      acc = fmaf(g ? v2.y : v2.x, fc1_w[d * 128 + u], acc);
    }
    red[g][d] = fmaxf(acc, 0.f) * fc2_w[d];
  }
  __syncthreads();
  if (tid < 2) {
    float s = fc2_b[0];
    for (int d = 0; d < 64; d++) s += red[tid][d];
    out[b0 + tid] = s;
  }
}

// ------------------------------- launcher ----------------------------------
extern "C" void kernel_launch(void* const* d_in, const int* in_sizes, int n_in,
                              void* d_out, int out_size, void* d_ws, size_t ws_size,
                              hipStream_t stream) {
  (void)in_sizes; (void)n_in; (void)out_size; (void)ws_size;
  char* ws = (char*)d_ws;
  // 32MB envelope, time-multiplexed:
  //   P1 [0,16M) live conv1->conv2; tables [0,448K) after conv2 (prep);
  //   feats [16M,32M) live conv2->lnn.
  float*  P1   = (float*)(ws);
  float*  feats= (float*)(ws + (16 << 20));
  float2* R12T = (float2*)(ws + 0);             // 128KB
  float*  VTT  = (float*)(ws + (128 << 10));    // 64KB
  float4* S4T  = (float4*)(ws + (192 << 10));   // 256KB -> ends 448KB

  conv1_kernel<<<512, 512, 0, stream>>>((const float*)d_in[0],
      (const float*)d_in[1], (const float*)d_in[2], P1);
  conv2_kernel<<<512, 512, 0, stream>>>(P1,
      (const float*)d_in[3], (const float*)d_in[4], feats);
  prep_kernel<<<64, 256, 0, stream>>>(
      (const float*)d_in[7], (const float*)d_in[8],
      (const float*)d_in[9], (const float*)d_in[10],
      (const float*)d_in[11], (const float*)d_in[12],
      (const float*)d_in[13], (const float*)d_in[14],
      (const float*)d_in[5], (const float*)d_in[6],
      R12T, VTT, S4T);
  lnn_kernel<<<256, 1024, 0, stream>>>(R12T, VTT, S4T, feats,
      (const float*)d_in[17], (const float*)d_in[16], (const float*)d_in[15],
      (const float*)d_in[18], (const float*)d_in[19],
      (const float*)d_in[20], (const float*)d_in[21],
      (float*)d_out);
}